// Round 5
// baseline (912.297 us; speedup 1.0000x reference)
//
#include <hip/hip_runtime.h>
#include <hip/hip_bf16.h>

#define T_TOK 2048
#define D_HID 2048
#define F_INT 1408
#define N_EXP 32
#define TOPK 6
#define NJOBS 34
#define SH_BASE 12288          // routed rows always sum to T_TOK*TOPK = 12288
#define ROWS_TOTAL 16384       // + 2*2048 shared
#define MAXT_GU 288            // sum ceil(cnt/64) <= 224 routed + 64 shared
#define MAXT_DN 159            // sum ceil(cnt/128) <= 127 routed + 32 shared
#define LDSW 40                // padded LDS row stride in bf16 (80 B): bank rotate 20/row

typedef __bf16 bf16;
typedef __bf16 bf16x4 __attribute__((ext_vector_type(4)));
typedef __bf16 bf16x8 __attribute__((ext_vector_type(8)));
typedef float f32x4 __attribute__((ext_vector_type(4)));

#define BAR() asm volatile("s_waitcnt lgkmcnt(0)\n\ts_barrier" ::: "memory")

// 16B-granule XOR swizzle: conflict-free (verified by bank arithmetic) for
// b128 writes of [n][k-block], b128 frag reads of 16-consecutive-rows, and
// b128 A-writes. granule = (k>>3) ^ ((r>>3)&3); row stride 40 elem = 80 B.
__device__ __forceinline__ int swz16(int r, int k) {
    return r * LDSW + (((k >> 3) ^ ((r >> 3) & 3)) << 3) + (k & 7);
}

// bid -> (job, n0, m0); job -> n0 outer -> m0 inner, m204 bijective XCD chunking
__device__ __forceinline__ int decode_tile(const int* __restrict__ counts, int bid,
                                           int NBN, int MSH, int NSH,
                                           int& job, int& n0, int& m0) {
    int total = 0;
    for (int j = 0; j < NJOBS; ++j) {
        int c = (j < N_EXP) ? counts[j] : T_TOK;
        total += ((c + (1 << MSH) - 1) >> MSH) * NBN;
    }
    if (bid >= total) return 0;
    int q = total >> 3, r = total & 7, x = bid & 7, o = bid >> 3;
    int L = (x < r ? x * (q + 1) : r * (q + 1) + (x - r) * q) + o;
    int acc = 0;
    for (int j = 0; j < NJOBS; ++j) {
        int c = (j < N_EXP) ? counts[j] : T_TOK;
        int tc = (c + (1 << MSH) - 1) >> MSH;
        int b = tc * NBN;
        if (L < acc + b) {
            int rem = L - acc;
            int n0i = rem / tc;
            job = j;
            n0 = n0i << NSH;
            m0 = (rem - n0i * tc) << MSH;
            return 1;
        }
        acc += b;
    }
    return 0;
}

// ---------------- router ----------------
__global__ __launch_bounds__(256) void k_router(const float* __restrict__ x,
                                                const float* __restrict__ wr,
                                                int* __restrict__ counts,
                                                int* __restrict__ tok_e,
                                                float* __restrict__ tok_w) {
    int t = blockIdx.x;
    int tid = threadIdx.x;
    __shared__ float xs[D_HID];
    __shared__ float part[8][32];
    __shared__ float probs[N_EXP];

    const float4* xsrc = (const float4*)(x + (size_t)t * D_HID);
    float4* xdst = (float4*)xs;
    for (int i = tid; i < D_HID / 4; i += 256) xdst[i] = xsrc[i];
    __syncthreads();

    int e = tid & 31, c = tid >> 5;
    float p = 0.f;
    const float* wp = wr + e;
    #pragma unroll 8
    for (int h = c * 256; h < c * 256 + 256; ++h) p += xs[h] * wp[h * 32];
    part[c][e] = p;
    __syncthreads();

    if (tid < 32) {
        float l = 0.f;
        #pragma unroll
        for (int cc = 0; cc < 8; ++cc) l += part[cc][tid];
        float m = l;
        for (int off = 16; off; off >>= 1) m = fmaxf(m, __shfl_xor(m, off));
        float ex = __expf(l - m);
        float s = ex;
        for (int off = 16; off; off >>= 1) s += __shfl_xor(s, off);
        probs[tid] = ex / s;
    }
    __syncthreads();

    if (tid == 0) {
        unsigned used = 0;
        int ids[TOPK]; float wsv[TOPK]; float wsum = 0.f;
        for (int k = 0; k < TOPK; ++k) {
            int best = 0; float bv = -1.f;
            for (int ee = 0; ee < N_EXP; ++ee)
                if (!((used >> ee) & 1u) && probs[ee] > bv) { bv = probs[ee]; best = ee; }
            used |= 1u << best;
            ids[k] = best; wsv[k] = bv; wsum += bv;
        }
        float inv = 1.f / wsum;
        for (int k = 0; k < TOPK; ++k) {
            tok_e[t * TOPK + k] = ids[k];
            tok_w[t * TOPK + k] = wsv[k] * inv;
            atomicAdd(&counts[ids[k]], 1);
        }
    }
}

// ---------------- plan ----------------
__global__ void k_plan(const int* __restrict__ counts, int* __restrict__ offs,
                       int* __restrict__ cursors) {
    int tid = threadIdx.x;
    if (tid < N_EXP) cursors[tid] = 0;
    if (tid == 0) {
        int o = 0;
        offs[0] = 0;
        for (int e2 = 0; e2 < N_EXP; ++e2) { o += counts[e2]; offs[e2 + 1] = o; }
        offs[33] = offs[32] + T_TOK;
        offs[34] = offs[33] + T_TOK;
    }
}

// ---------------- assign ----------------
__global__ __launch_bounds__(256) void k_assign(const int* __restrict__ tok_e,
                                                const int* __restrict__ offs,
                                                int* __restrict__ cursors,
                                                int* __restrict__ slots,
                                                int* __restrict__ rowtok) {
    int t = blockIdx.x * 256 + threadIdx.x;
    #pragma unroll
    for (int k = 0; k < TOPK; ++k) {
        int e = tok_e[t * TOPK + k];
        int pos = atomicAdd(&cursors[e], 1);
        int slot = offs[e] + pos;
        slots[t * TOPK + k] = slot;
        rowtok[slot] = t;
    }
    rowtok[SH_BASE + t] = t;
    rowtok[SH_BASE + T_TOK + t] = t;
}

// ---------------- GEMM1: H = silu(X Wg) * (X Wu) ----------------
// Tile 64(M) x 128(N), BK=32, 4 waves of 32x64, dbuf LDS, 1 barrier/iter.
// All LDS ops are b128 on the conflict-free swz16 layout.
__global__ __launch_bounds__(256, 3) void k_gateup(
    const float* __restrict__ x, const float* __restrict__ wg, const float* __restrict__ wu,
    const float* __restrict__ sg, const float* __restrict__ su,
    const int* __restrict__ rowtok, const int* __restrict__ counts, const int* __restrict__ offs,
    bf16* __restrict__ H) {

    int job, n0, m0;
    if (!decode_tile(counts, blockIdx.x, F_INT / 128, 6, 7, job, n0, m0)) return;
    int cnt = (job < N_EXP) ? counts[job] : T_TOK;
    int base = offs[job];
    const float* Wg = (job < N_EXP) ? wg + (size_t)job * D_HID * F_INT
                                    : sg + (size_t)(job - N_EXP) * D_HID * F_INT;
    const float* Wu = (job < N_EXP) ? wu + (size_t)job * D_HID * F_INT
                                    : su + (size_t)(job - N_EXP) * D_HID * F_INT;

    __shared__ bf16 As[2][64 * LDSW];
    __shared__ bf16 Bg[2][128 * LDSW];
    __shared__ bf16 Bu[2][128 * LDSW];

    int tid = threadIdx.x;
    int lane = tid & 63;
    int wid = tid >> 6;
    int wm = (wid >> 1) * 32;
    int wn = (wid & 1) * 64;

    // A staging: thread -> (row ar, 8-elem k-chunk akg)
    int ar = tid >> 2;
    int akg = tid & 3;
    int grow_a = m0 + ar; if (grow_a > cnt - 1) grow_a = cnt - 1;
    const float* asrc = x + (size_t)rowtok[base + grow_a] * D_HID + akg * 8;

    // B staging: thread -> 2 n-cols (bn, bn+1) x 8 k-rows (bkg block)
    int bn = (tid & 63) * 2;
    int bkg = tid >> 6;                     // 0..3
    const float* gsrc = Wg + (size_t)(bkg * 8) * F_INT + n0 + bn;
    const float* usrc = Wu + (size_t)(bkg * 8) * F_INT + n0 + bn;

    f32x4 accg[2][4], accu[2][4];
    f32x4 zero = {0.f, 0.f, 0.f, 0.f};
    #pragma unroll
    for (int i = 0; i < 2; ++i)
        #pragma unroll
        for (int j = 0; j < 4; ++j) { accg[i][j] = zero; accu[i][j] = zero; }

    float4 a_r[2];
    float2 g_r[8], u_r[8];

    auto LOAD = [&](int k0) {
        a_r[0] = *(const float4*)(asrc + k0);
        a_r[1] = *(const float4*)(asrc + k0 + 4);
        #pragma unroll
        for (int j = 0; j < 8; ++j)
            g_r[j] = *(const float2*)(gsrc + (size_t)(k0 + j) * F_INT);
        #pragma unroll
        for (int j = 0; j < 8; ++j)
            u_r[j] = *(const float2*)(usrc + (size_t)(k0 + j) * F_INT);
    };

    auto WRITE = [&](int s) {
        bf16x8 av = {(bf16)a_r[0].x, (bf16)a_r[0].y, (bf16)a_r[0].z, (bf16)a_r[0].w,
                     (bf16)a_r[1].x, (bf16)a_r[1].y, (bf16)a_r[1].z, (bf16)a_r[1].w};
        *(bf16x8*)&As[s][swz16(ar, akg * 8)] = av;
        bf16x8 g0 = {(bf16)g_r[0].x, (bf16)g_r[1].x, (bf16)g_r[2].x, (bf16)g_r[3].x,
                     (bf16)g_r[4].x, (bf16)g_r[5].x, (bf16)g_r[6].x, (bf16)g_r[7].x};
        bf16x8 g1 = {(bf16)g_r[0].y, (bf16)g_r[1].y, (bf16)g_r[2].y, (bf16)g_r[3].y,
                     (bf16)g_r[4].y, (bf16)g_r[5].y, (bf16)g_r[6].y, (bf16)g_r[7].y};
        *(bf16x8*)&Bg[s][swz16(bn, bkg * 8)] = g0;
        *(bf16x8*)&Bg[s][swz16(bn + 1, bkg * 8)] = g1;
        bf16x8 u0 = {(bf16)u_r[0].x, (bf16)u_r[1].x, (bf16)u_r[2].x, (bf16)u_r[3].x,
                     (bf16)u_r[4].x, (bf16)u_r[5].x, (bf16)u_r[6].x, (bf16)u_r[7].x};
        bf16x8 u1 = {(bf16)u_r[0].y, (bf16)u_r[1].y, (bf16)u_r[2].y, (bf16)u_r[3].y,
                     (bf16)u_r[4].y, (bf16)u_r[5].y, (bf16)u_r[6].y, (bf16)u_r[7].y};
        *(bf16x8*)&Bu[s][swz16(bn, bkg * 8)] = u0;
        *(bf16x8*)&Bu[s][swz16(bn + 1, bkg * 8)] = u1;
    };

    const int NT = D_HID / 32;
    LOAD(0);
    WRITE(0);
    LOAD(32);
    BAR();

    for (int kt = 0; kt < NT; ++kt) {
        int cur = kt & 1;
        if (kt + 1 < NT) WRITE(cur ^ 1);         // stage tile kt+1
        if (kt + 2 < NT) LOAD((kt + 2) * 32);    // in flight across this iter

        int kgl = (lane >> 4) * 8;
        bf16x8 af[2];
        #pragma unroll
        for (int mf = 0; mf < 2; ++mf)
            af[mf] = *(const bf16x8*)&As[cur][swz16(wm + mf * 16 + (lane & 15), kgl)];
        #pragma unroll
        for (int nf = 0; nf < 4; ++nf) {
            int rn = wn + nf * 16 + (lane & 15);
            bf16x8 bfr = *(const bf16x8*)&Bg[cur][swz16(rn, kgl)];
            bf16x8 ufr = *(const bf16x8*)&Bu[cur][swz16(rn, kgl)];
            #pragma unroll
            for (int mf = 0; mf < 2; ++mf) {
                accg[mf][nf] = __builtin_amdgcn_mfma_f32_16x16x32_bf16(af[mf], bfr, accg[mf][nf], 0, 0, 0);
                accu[mf][nf] = __builtin_amdgcn_mfma_f32_16x16x32_bf16(af[mf], ufr, accu[mf][nf], 0, 0, 0);
            }
        }
        BAR();
    }

    // epilogue: h = silu(g) * u -> bf16 H
    #pragma unroll
    for (int mf = 0; mf < 2; ++mf) {
        #pragma unroll
        for (int nf = 0; nf < 4; ++nf) {
            int col = n0 + wn + nf * 16 + (lane & 15);
            #pragma unroll
            for (int r = 0; r < 4; ++r) {
                int grow = m0 + wm + mf * 16 + (lane >> 4) * 4 + r;
                if (grow < cnt) {
                    float g = accg[mf][nf][r];
                    float u = accu[mf][nf][r];
                    float h = g * u / (1.f + __expf(-g));
                    H[(size_t)(base + grow) * F_INT + col] = (bf16)h;
                }
            }
        }
    }
}

// ---------------- GEMM2: P = H Wd ----------------
// Tile 128x128, BK=32, 4 waves of 64x64, dbuf LDS, 1 barrier/iter, b128-only LDS.
__global__ __launch_bounds__(256, 3) void k_down(
    const bf16* __restrict__ H, const float* __restrict__ wd, const float* __restrict__ sd,
    const int* __restrict__ counts, const int* __restrict__ offs,
    bf16* __restrict__ P) {

    int job, n0, m0;
    if (!decode_tile(counts, blockIdx.x, D_HID / 128, 7, 7, job, n0, m0)) return;
    int cnt = (job < N_EXP) ? counts[job] : T_TOK;
    int base = offs[job];
    const float* Wd = (job < N_EXP) ? wd + (size_t)job * F_INT * D_HID
                                    : sd + (size_t)(job - N_EXP) * F_INT * D_HID;

    __shared__ bf16 As[2][128 * LDSW];
    __shared__ bf16 Bs[2][128 * LDSW];

    int tid = threadIdx.x;
    int lane = tid & 63;
    int wid = tid >> 6;
    int wm = (wid >> 1) * 64;
    int wn = (wid & 1) * 64;

    // A staging: thread -> row ar, two 8-elem k-chunks (bf16 source: pure copy)
    int ar = tid >> 1;
    int akg2 = (tid & 1) * 2;               // k-chunk base: 0 or 2
    int grow_a = m0 + ar; if (grow_a > cnt - 1) grow_a = cnt - 1;
    const bf16* asrc = H + (size_t)(base + grow_a) * F_INT + akg2 * 8;

    // B staging: thread -> 2 n-cols x 8 k-rows
    int bn = (tid & 63) * 2;
    int bkg = tid >> 6;
    const float* bsrc = Wd + (size_t)(bkg * 8) * D_HID + n0 + bn;

    f32x4 acc[4][4];
    f32x4 zero = {0.f, 0.f, 0.f, 0.f};
    #pragma unroll
    for (int i = 0; i < 4; ++i)
        #pragma unroll
        for (int j = 0; j < 4; ++j) acc[i][j] = zero;

    bf16x8 h_r[2];
    float2 b_r[8];

    auto LOAD = [&](int k0) {
        h_r[0] = *(const bf16x8*)(asrc + k0);
        h_r[1] = *(const bf16x8*)(asrc + k0 + 8);
        #pragma unroll
        for (int j = 0; j < 8; ++j)
            b_r[j] = *(const float2*)(bsrc + (size_t)(k0 + j) * D_HID);
    };

    auto WRITE = [&](int s) {
        *(bf16x8*)&As[s][swz16(ar, akg2 * 8)] = h_r[0];
        *(bf16x8*)&As[s][swz16(ar, (akg2 + 1) * 8)] = h_r[1];
        bf16x8 b0 = {(bf16)b_r[0].x, (bf16)b_r[1].x, (bf16)b_r[2].x, (bf16)b_r[3].x,
                     (bf16)b_r[4].x, (bf16)b_r[5].x, (bf16)b_r[6].x, (bf16)b_r[7].x};
        bf16x8 b1 = {(bf16)b_r[0].y, (bf16)b_r[1].y, (bf16)b_r[2].y, (bf16)b_r[3].y,
                     (bf16)b_r[4].y, (bf16)b_r[5].y, (bf16)b_r[6].y, (bf16)b_r[7].y};
        *(bf16x8*)&Bs[s][swz16(bn, bkg * 8)] = b0;
        *(bf16x8*)&Bs[s][swz16(bn + 1, bkg * 8)] = b1;
    };

    const int NT = F_INT / 32;
    LOAD(0);
    WRITE(0);
    LOAD(32);
    BAR();

    for (int kt = 0; kt < NT; ++kt) {
        int cur = kt & 1;
        if (kt + 1 < NT) WRITE(cur ^ 1);
        if (kt + 2 < NT) LOAD((kt + 2) * 32);

        int kgl = (lane >> 4) * 8;
        bf16x8 af[4];
        #pragma unroll
        for (int mf = 0; mf < 4; ++mf)
            af[mf] = *(const bf16x8*)&As[cur][swz16(wm + mf * 16 + (lane & 15), kgl)];
        #pragma unroll
        for (int nf = 0; nf < 4; ++nf) {
            int rn = wn + nf * 16 + (lane & 15);
            bf16x8 bfr = *(const bf16x8*)&Bs[cur][swz16(rn, kgl)];
            #pragma unroll
            for (int mf = 0; mf < 4; ++mf)
                acc[mf][nf] = __builtin_amdgcn_mfma_f32_16x16x32_bf16(af[mf], bfr, acc[mf][nf], 0, 0, 0);
        }
        BAR();
    }

    #pragma unroll
    for (int mf = 0; mf < 4; ++mf) {
        #pragma unroll
        for (int nf = 0; nf < 4; ++nf) {
            int col = n0 + wn + nf * 16 + (lane & 15);
            #pragma unroll
            for (int r = 0; r < 4; ++r) {
                int grow = m0 + wm + mf * 16 + (lane >> 4) * 4 + r;
                if (grow < cnt)
                    P[(size_t)(base + grow) * D_HID + col] = (bf16)acc[mf][nf][r];
            }
        }
    }
}

// ---------------- combine ----------------
__global__ __launch_bounds__(256) void k_combine(const bf16* __restrict__ P,
                                                 const int* __restrict__ slots,
                                                 const float* __restrict__ tok_w,
                                                 float* __restrict__ out) {
    int t = blockIdx.x;
    int tid = threadIdx.x;
    __shared__ int ss[TOPK];
    __shared__ float ww[TOPK];
    if (tid < TOPK) { ss[tid] = slots[t * TOPK + tid]; ww[tid] = tok_w[t * TOPK + tid]; }
    __syncthreads();
    int c0 = tid * 8;
    float acc[8];
    {
        bf16x8 v0 = *(const bf16x8*)(P + (size_t)(SH_BASE + t) * D_HID + c0);
        bf16x8 v1 = *(const bf16x8*)(P + (size_t)(SH_BASE + T_TOK + t) * D_HID + c0);
        #pragma unroll
        for (int i = 0; i < 8; ++i) acc[i] = (float)v0[i] + (float)v1[i];
    }
    #pragma unroll
    for (int k = 0; k < TOPK; ++k) {
        bf16x8 v = *(const bf16x8*)(P + (size_t)ss[k] * D_HID + c0);
        float w = ww[k];
        #pragma unroll
        for (int i = 0; i < 8; ++i) acc[i] += w * (float)v[i];
    }
    float4 o0 = {acc[0], acc[1], acc[2], acc[3]};
    float4 o1 = {acc[4], acc[5], acc[6], acc[7]};
    *(float4*)(out + (size_t)t * D_HID + c0) = o0;
    *(float4*)(out + (size_t)t * D_HID + c0 + 4) = o1;
}

extern "C" void kernel_launch(void* const* d_in, const int* in_sizes, int n_in,
                              void* d_out, int out_size, void* d_ws, size_t ws_size,
                              hipStream_t stream) {
    const float* x  = (const float*)d_in[0];
    const float* wr = (const float*)d_in[1];
    const float* wg = (const float*)d_in[2];
    const float* wu = (const float*)d_in[3];
    const float* wd = (const float*)d_in[4];
    const float* sg = (const float*)d_in[5];
    const float* su = (const float*)d_in[6];
    const float* sd = (const float*)d_in[7];
    float* out = (float*)d_out;

    char* w = (char*)d_ws;
    int*   counts   = (int*)(w + 0);        // 32 ints
    int*   cursors  = (int*)(w + 256);      // 32 ints
    int*   offs     = (int*)(w + 512);      // 35 ints
    int*   tok_e    = (int*)(w + 8192);                 // 12288 ints
    float* tok_w    = (float*)(w + 8192 + 49152);       // 12288 floats
    int*   slots    = (int*)(w + 8192 + 2 * 49152);     // 12288 ints
    int*   rowtok   = (int*)(w + 8192 + 3 * 49152);     // 16384 ints
    bf16*  H        = (bf16*)(w + 262144);                                  // 16384 x 1408 bf16
    bf16*  P        = (bf16*)(w + 262144 + (size_t)ROWS_TOTAL * F_INT * 2); // 16384 x 2048 bf16

    hipMemsetAsync(counts, 0, 128, stream);
    k_router<<<T_TOK, 256, 0, stream>>>(x, wr, counts, tok_e, tok_w);
    k_plan<<<1, 64, 0, stream>>>(counts, offs, cursors);
    k_assign<<<T_TOK / 256, 256, 0, stream>>>(tok_e, offs, cursors, slots, rowtok);
    k_gateup<<<MAXT_GU * (F_INT / 128), 256, 0, stream>>>(
        x, wg, wu, sg, su, rowtok, counts, offs, H);
    k_down<<<MAXT_DN * (D_HID / 128), 256, 0, stream>>>(
        H, wd, sd, counts, offs, P);
    k_combine<<<T_TOK, 256, 0, stream>>>(P, slots, tok_w, out);
}

// Round 6
// 777.102 us; speedup vs baseline: 1.1740x; 1.1740x over previous
//
#include <hip/hip_runtime.h>
#include <hip/hip_bf16.h>

#define T_TOK 2048
#define D_HID 2048
#define F_INT 1408
#define N_EXP 32
#define TOPK 6
#define NJOBS 34
#define SH_BASE 12288          // routed rows always sum to T_TOK*TOPK = 12288
#define ROWS_TOTAL 16384       // + 2*2048 shared
#define MAXT_GU 288            // sum ceil(cnt/64) <= 224 routed + 64 shared
#define MAXT_DN 159            // sum ceil(cnt/128) <= 127 routed + 32 shared
#define LDSW 40                // LDS row stride in bf16 (80 B): 20-bank/row rotation

typedef __bf16 bf16;
typedef __bf16 bf16x4 __attribute__((ext_vector_type(4)));
typedef __bf16 bf16x8 __attribute__((ext_vector_type(8)));
typedef float f32x4 __attribute__((ext_vector_type(4)));

#define BAR() asm volatile("s_waitcnt lgkmcnt(0)\n\ts_barrier" ::: "memory")

// 16B-granule XOR swizzle. Verified lane-by-lane conflict-free for:
//  - b128 frag reads (16 consecutive rows x 4 k-granule quarters)
//  - b128 A-writes (4 granules per row, granule-permuted)
//  - b64 transposed B-writes (4-row micro-tiles, k4 halves split bank parity)
__device__ __forceinline__ int swz16(int r, int k) {
    return r * LDSW + (((k >> 3) ^ ((r >> 3) & 3)) << 3) + (k & 7);
}

// bid -> (job, n0, m0); job -> n0 outer -> m0 inner, m204 bijective XCD chunking
__device__ __forceinline__ int decode_tile(const int* __restrict__ counts, int bid,
                                           int NBN, int MSH, int NSH,
                                           int& job, int& n0, int& m0) {
    int total = 0;
    for (int j = 0; j < NJOBS; ++j) {
        int c = (j < N_EXP) ? counts[j] : T_TOK;
        total += ((c + (1 << MSH) - 1) >> MSH) * NBN;
    }
    if (bid >= total) return 0;
    int q = total >> 3, r = total & 7, x = bid & 7, o = bid >> 3;
    int L = (x < r ? x * (q + 1) : r * (q + 1) + (x - r) * q) + o;
    int acc = 0;
    for (int j = 0; j < NJOBS; ++j) {
        int c = (j < N_EXP) ? counts[j] : T_TOK;
        int tc = (c + (1 << MSH) - 1) >> MSH;
        int b = tc * NBN;
        if (L < acc + b) {
            int rem = L - acc;
            int n0i = rem / tc;
            job = j;
            n0 = n0i << NSH;
            m0 = (rem - n0i * tc) << MSH;
            return 1;
        }
        acc += b;
    }
    return 0;
}

// ---------------- X fp32 -> bf16 (one cheap pass) ----------------
__global__ __launch_bounds__(256) void k_xcvt(const float* __restrict__ x,
                                              bf16* __restrict__ xb) {
    int i = blockIdx.x * 2048 + threadIdx.x * 8;
    float4 f0 = *(const float4*)(x + i);
    float4 f1 = *(const float4*)(x + i + 4);
    bf16x8 v = {(bf16)f0.x, (bf16)f0.y, (bf16)f0.z, (bf16)f0.w,
                (bf16)f1.x, (bf16)f1.y, (bf16)f1.z, (bf16)f1.w};
    *(bf16x8*)(xb + i) = v;
}

// ---------------- router ----------------
__global__ __launch_bounds__(256) void k_router(const float* __restrict__ x,
                                                const float* __restrict__ wr,
                                                int* __restrict__ counts,
                                                int* __restrict__ tok_e,
                                                float* __restrict__ tok_w) {
    int t = blockIdx.x;
    int tid = threadIdx.x;
    __shared__ float xs[D_HID];
    __shared__ float part[8][32];
    __shared__ float probs[N_EXP];

    const float4* xsrc = (const float4*)(x + (size_t)t * D_HID);
    float4* xdst = (float4*)xs;
    for (int i = tid; i < D_HID / 4; i += 256) xdst[i] = xsrc[i];
    __syncthreads();

    int e = tid & 31, c = tid >> 5;
    float p = 0.f;
    const float* wp = wr + e;
    #pragma unroll 8
    for (int h = c * 256; h < c * 256 + 256; ++h) p += xs[h] * wp[h * 32];
    part[c][e] = p;
    __syncthreads();

    if (tid < 32) {
        float l = 0.f;
        #pragma unroll
        for (int cc = 0; cc < 8; ++cc) l += part[cc][tid];
        float m = l;
        for (int off = 16; off; off >>= 1) m = fmaxf(m, __shfl_xor(m, off));
        float ex = __expf(l - m);
        float s = ex;
        for (int off = 16; off; off >>= 1) s += __shfl_xor(s, off);
        probs[tid] = ex / s;
    }
    __syncthreads();

    if (tid == 0) {
        unsigned used = 0;
        int ids[TOPK]; float wsv[TOPK]; float wsum = 0.f;
        for (int k = 0; k < TOPK; ++k) {
            int best = 0; float bv = -1.f;
            for (int ee = 0; ee < N_EXP; ++ee)
                if (!((used >> ee) & 1u) && probs[ee] > bv) { bv = probs[ee]; best = ee; }
            used |= 1u << best;
            ids[k] = best; wsv[k] = bv; wsum += bv;
        }
        float inv = 1.f / wsum;
        for (int k = 0; k < TOPK; ++k) {
            tok_e[t * TOPK + k] = ids[k];
            tok_w[t * TOPK + k] = wsv[k] * inv;
            atomicAdd(&counts[ids[k]], 1);
        }
    }
}

// ---------------- plan ----------------
__global__ void k_plan(const int* __restrict__ counts, int* __restrict__ offs,
                       int* __restrict__ cursors) {
    int tid = threadIdx.x;
    if (tid < N_EXP) cursors[tid] = 0;
    if (tid == 0) {
        int o = 0;
        offs[0] = 0;
        for (int e2 = 0; e2 < N_EXP; ++e2) { o += counts[e2]; offs[e2 + 1] = o; }
        offs[33] = offs[32] + T_TOK;
        offs[34] = offs[33] + T_TOK;
    }
}

// ---------------- assign ----------------
__global__ __launch_bounds__(256) void k_assign(const int* __restrict__ tok_e,
                                                const int* __restrict__ offs,
                                                int* __restrict__ cursors,
                                                int* __restrict__ slots,
                                                int* __restrict__ rowtok) {
    int t = blockIdx.x * 256 + threadIdx.x;
    #pragma unroll
    for (int k = 0; k < TOPK; ++k) {
        int e = tok_e[t * TOPK + k];
        int pos = atomicAdd(&cursors[e], 1);
        int slot = offs[e] + pos;
        slots[t * TOPK + k] = slot;
        rowtok[slot] = t;
    }
    rowtok[SH_BASE + t] = t;
    rowtok[SH_BASE + T_TOK + t] = t;
}

// ---------------- GEMM1: H = silu(X Wg) * (X Wu) ----------------
// Tile 64(M) x 128(N), BK=32, 4 waves of 32x64, dbuf LDS, 1 barrier/iter.
// A: bf16 copy staging (from precvt X). B: float4 loads + b64 transposed writes.
__global__ __launch_bounds__(256, 3) void k_gateup(
    const bf16* __restrict__ xb, const float* __restrict__ wg, const float* __restrict__ wu,
    const float* __restrict__ sg, const float* __restrict__ su,
    const int* __restrict__ rowtok, const int* __restrict__ counts, const int* __restrict__ offs,
    bf16* __restrict__ H) {

    int job, n0, m0;
    if (!decode_tile(counts, blockIdx.x, F_INT / 128, 6, 7, job, n0, m0)) return;
    int cnt = (job < N_EXP) ? counts[job] : T_TOK;
    int base = offs[job];
    const float* Wg = (job < N_EXP) ? wg + (size_t)job * D_HID * F_INT
                                    : sg + (size_t)(job - N_EXP) * D_HID * F_INT;
    const float* Wu = (job < N_EXP) ? wu + (size_t)job * D_HID * F_INT
                                    : su + (size_t)(job - N_EXP) * D_HID * F_INT;

    __shared__ bf16 As[2][64 * LDSW];
    __shared__ bf16 Bg[2][128 * LDSW];
    __shared__ bf16 Bu[2][128 * LDSW];

    int tid = threadIdx.x;
    int lane = tid & 63;
    int wid = tid >> 6;
    int wm = (wid >> 1) * 32;
    int wn = (wid & 1) * 64;

    // A staging: thread -> (row ar, 8-elem k-granule akg), pure bf16 copy
    int ar = tid >> 2;
    int akg = tid & 3;
    int grow_a = m0 + ar; if (grow_a > cnt - 1) grow_a = cnt - 1;
    const bf16* asrc = xb + (size_t)rowtok[base + grow_a] * D_HID + akg * 8;

    // B staging: thread -> 4 k-rows x 4 n-cols (float4 loads, b64 transposed writes)
    int k4 = (tid >> 5) * 4;
    int nn = (tid & 31) * 4;
    const float* gsrc = Wg + (size_t)k4 * F_INT + n0 + nn;
    const float* usrc = Wu + (size_t)k4 * F_INT + n0 + nn;

    f32x4 accg[2][4], accu[2][4];
    f32x4 zero = {0.f, 0.f, 0.f, 0.f};
    #pragma unroll
    for (int i = 0; i < 2; ++i)
        #pragma unroll
        for (int j = 0; j < 4; ++j) { accg[i][j] = zero; accu[i][j] = zero; }

    bf16x8 a_r8;
    float4 g_r[4], u_r[4];

    auto LOAD = [&](int k0) {
        a_r8 = *(const bf16x8*)(asrc + k0);
        const float* g0 = gsrc + (size_t)k0 * F_INT;
        g_r[0] = *(const float4*)g0;
        g_r[1] = *(const float4*)(g0 + F_INT);
        g_r[2] = *(const float4*)(g0 + 2 * F_INT);
        g_r[3] = *(const float4*)(g0 + 3 * F_INT);
        const float* u0 = usrc + (size_t)k0 * F_INT;
        u_r[0] = *(const float4*)u0;
        u_r[1] = *(const float4*)(u0 + F_INT);
        u_r[2] = *(const float4*)(u0 + 2 * F_INT);
        u_r[3] = *(const float4*)(u0 + 3 * F_INT);
    };

    auto WRITE = [&](int s) {
        *(bf16x8*)&As[s][swz16(ar, akg * 8)] = a_r8;
        bf16x4 p0 = {(bf16)g_r[0].x, (bf16)g_r[1].x, (bf16)g_r[2].x, (bf16)g_r[3].x};
        bf16x4 p1 = {(bf16)g_r[0].y, (bf16)g_r[1].y, (bf16)g_r[2].y, (bf16)g_r[3].y};
        bf16x4 p2 = {(bf16)g_r[0].z, (bf16)g_r[1].z, (bf16)g_r[2].z, (bf16)g_r[3].z};
        bf16x4 p3 = {(bf16)g_r[0].w, (bf16)g_r[1].w, (bf16)g_r[2].w, (bf16)g_r[3].w};
        *(bf16x4*)&Bg[s][swz16(nn + 0, k4)] = p0;
        *(bf16x4*)&Bg[s][swz16(nn + 1, k4)] = p1;
        *(bf16x4*)&Bg[s][swz16(nn + 2, k4)] = p2;
        *(bf16x4*)&Bg[s][swz16(nn + 3, k4)] = p3;
        bf16x4 q0 = {(bf16)u_r[0].x, (bf16)u_r[1].x, (bf16)u_r[2].x, (bf16)u_r[3].x};
        bf16x4 q1 = {(bf16)u_r[0].y, (bf16)u_r[1].y, (bf16)u_r[2].y, (bf16)u_r[3].y};
        bf16x4 q2 = {(bf16)u_r[0].z, (bf16)u_r[1].z, (bf16)u_r[2].z, (bf16)u_r[3].z};
        bf16x4 q3 = {(bf16)u_r[0].w, (bf16)u_r[1].w, (bf16)u_r[2].w, (bf16)u_r[3].w};
        *(bf16x4*)&Bu[s][swz16(nn + 0, k4)] = q0;
        *(bf16x4*)&Bu[s][swz16(nn + 1, k4)] = q1;
        *(bf16x4*)&Bu[s][swz16(nn + 2, k4)] = q2;
        *(bf16x4*)&Bu[s][swz16(nn + 3, k4)] = q3;
    };

    const int NT = D_HID / 32;
    LOAD(0);
    WRITE(0);
    LOAD(32);
    BAR();

    for (int kt = 0; kt < NT; ++kt) {
        int cur = kt & 1;
        if (kt + 1 < NT) WRITE(cur ^ 1);         // stage tile kt+1
        if (kt + 2 < NT) LOAD((kt + 2) * 32);    // in flight across this iter

        int kgl = (lane >> 4) * 8;
        bf16x8 af[2];
        #pragma unroll
        for (int mf = 0; mf < 2; ++mf)
            af[mf] = *(const bf16x8*)&As[cur][swz16(wm + mf * 16 + (lane & 15), kgl)];
        #pragma unroll
        for (int nf = 0; nf < 4; ++nf) {
            int rn = wn + nf * 16 + (lane & 15);
            bf16x8 bfr = *(const bf16x8*)&Bg[cur][swz16(rn, kgl)];
            bf16x8 ufr = *(const bf16x8*)&Bu[cur][swz16(rn, kgl)];
            #pragma unroll
            for (int mf = 0; mf < 2; ++mf) {
                accg[mf][nf] = __builtin_amdgcn_mfma_f32_16x16x32_bf16(af[mf], bfr, accg[mf][nf], 0, 0, 0);
                accu[mf][nf] = __builtin_amdgcn_mfma_f32_16x16x32_bf16(af[mf], ufr, accu[mf][nf], 0, 0, 0);
            }
        }
        BAR();
    }

    // epilogue: h = silu(g) * u -> bf16 H
    #pragma unroll
    for (int mf = 0; mf < 2; ++mf) {
        #pragma unroll
        for (int nf = 0; nf < 4; ++nf) {
            int col = n0 + wn + nf * 16 + (lane & 15);
            #pragma unroll
            for (int r = 0; r < 4; ++r) {
                int grow = m0 + wm + mf * 16 + (lane >> 4) * 4 + r;
                if (grow < cnt) {
                    float g = accg[mf][nf][r];
                    float u = accu[mf][nf][r];
                    float h = g * u / (1.f + __expf(-g));
                    H[(size_t)(base + grow) * F_INT + col] = (bf16)h;
                }
            }
        }
    }
}

// ---------------- GEMM2: P = H Wd ----------------
// Tile 128x128, BK=32, 4 waves of 64x64, dbuf LDS, 1 barrier/iter.
__global__ __launch_bounds__(256, 3) void k_down(
    const bf16* __restrict__ H, const float* __restrict__ wd, const float* __restrict__ sd,
    const int* __restrict__ counts, const int* __restrict__ offs,
    bf16* __restrict__ P) {

    int job, n0, m0;
    if (!decode_tile(counts, blockIdx.x, D_HID / 128, 7, 7, job, n0, m0)) return;
    int cnt = (job < N_EXP) ? counts[job] : T_TOK;
    int base = offs[job];
    const float* Wd = (job < N_EXP) ? wd + (size_t)job * F_INT * D_HID
                                    : sd + (size_t)(job - N_EXP) * F_INT * D_HID;

    __shared__ bf16 As[2][128 * LDSW];
    __shared__ bf16 Bs[2][128 * LDSW];

    int tid = threadIdx.x;
    int lane = tid & 63;
    int wid = tid >> 6;
    int wm = (wid >> 1) * 64;
    int wn = (wid & 1) * 64;

    // A staging: thread -> row ar, two 8-elem k-granules (bf16 copy)
    int ar = tid >> 1;
    int akg2 = (tid & 1) * 2;
    int grow_a = m0 + ar; if (grow_a > cnt - 1) grow_a = cnt - 1;
    const bf16* asrc = H + (size_t)(base + grow_a) * F_INT + akg2 * 8;

    // B staging: thread -> 4 k-rows x 4 n-cols
    int k4 = (tid >> 5) * 4;
    int nn = (tid & 31) * 4;
    const float* bsrc = Wd + (size_t)k4 * D_HID + n0 + nn;

    f32x4 acc[4][4];
    f32x4 zero = {0.f, 0.f, 0.f, 0.f};
    #pragma unroll
    for (int i = 0; i < 4; ++i)
        #pragma unroll
        for (int j = 0; j < 4; ++j) acc[i][j] = zero;

    bf16x8 h_r[2];
    float4 b_r[4];

    auto LOAD = [&](int k0) {
        h_r[0] = *(const bf16x8*)(asrc + k0);
        h_r[1] = *(const bf16x8*)(asrc + k0 + 8);
        const float* b0 = bsrc + (size_t)k0 * D_HID;
        b_r[0] = *(const float4*)b0;
        b_r[1] = *(const float4*)(b0 + D_HID);
        b_r[2] = *(const float4*)(b0 + 2 * D_HID);
        b_r[3] = *(const float4*)(b0 + 3 * D_HID);
    };

    auto WRITE = [&](int s) {
        *(bf16x8*)&As[s][swz16(ar, akg2 * 8)] = h_r[0];
        *(bf16x8*)&As[s][swz16(ar, (akg2 + 1) * 8)] = h_r[1];
        bf16x4 p0 = {(bf16)b_r[0].x, (bf16)b_r[1].x, (bf16)b_r[2].x, (bf16)b_r[3].x};
        bf16x4 p1 = {(bf16)b_r[0].y, (bf16)b_r[1].y, (bf16)b_r[2].y, (bf16)b_r[3].y};
        bf16x4 p2 = {(bf16)b_r[0].z, (bf16)b_r[1].z, (bf16)b_r[2].z, (bf16)b_r[3].z};
        bf16x4 p3 = {(bf16)b_r[0].w, (bf16)b_r[1].w, (bf16)b_r[2].w, (bf16)b_r[3].w};
        *(bf16x4*)&Bs[s][swz16(nn + 0, k4)] = p0;
        *(bf16x4*)&Bs[s][swz16(nn + 1, k4)] = p1;
        *(bf16x4*)&Bs[s][swz16(nn + 2, k4)] = p2;
        *(bf16x4*)&Bs[s][swz16(nn + 3, k4)] = p3;
    };

    const int NT = F_INT / 32;
    LOAD(0);
    WRITE(0);
    LOAD(32);
    BAR();

    for (int kt = 0; kt < NT; ++kt) {
        int cur = kt & 1;
        if (kt + 1 < NT) WRITE(cur ^ 1);
        if (kt + 2 < NT) LOAD((kt + 2) * 32);

        int kgl = (lane >> 4) * 8;
        bf16x8 af[4];
        #pragma unroll
        for (int mf = 0; mf < 4; ++mf)
            af[mf] = *(const bf16x8*)&As[cur][swz16(wm + mf * 16 + (lane & 15), kgl)];
        #pragma unroll
        for (int nf = 0; nf < 4; ++nf) {
            int rn = wn + nf * 16 + (lane & 15);
            bf16x8 bfr = *(const bf16x8*)&Bs[cur][swz16(rn, kgl)];
            #pragma unroll
            for (int mf = 0; mf < 4; ++mf)
                acc[mf][nf] = __builtin_amdgcn_mfma_f32_16x16x32_bf16(af[mf], bfr, acc[mf][nf], 0, 0, 0);
        }
        BAR();
    }

    #pragma unroll
    for (int mf = 0; mf < 4; ++mf) {
        #pragma unroll
        for (int nf = 0; nf < 4; ++nf) {
            int col = n0 + wn + nf * 16 + (lane & 15);
            #pragma unroll
            for (int r = 0; r < 4; ++r) {
                int grow = m0 + wm + mf * 16 + (lane >> 4) * 4 + r;
                if (grow < cnt)
                    P[(size_t)(base + grow) * D_HID + col] = (bf16)acc[mf][nf][r];
            }
        }
    }
}

// ---------------- combine ----------------
__global__ __launch_bounds__(256) void k_combine(const bf16* __restrict__ P,
                                                 const int* __restrict__ slots,
                                                 const float* __restrict__ tok_w,
                                                 float* __restrict__ out) {
    int t = blockIdx.x;
    int tid = threadIdx.x;
    __shared__ int ss[TOPK];
    __shared__ float ww[TOPK];
    if (tid < TOPK) { ss[tid] = slots[t * TOPK + tid]; ww[tid] = tok_w[t * TOPK + tid]; }
    __syncthreads();
    int c0 = tid * 8;
    float acc[8];
    {
        bf16x8 v0 = *(const bf16x8*)(P + (size_t)(SH_BASE + t) * D_HID + c0);
        bf16x8 v1 = *(const bf16x8*)(P + (size_t)(SH_BASE + T_TOK + t) * D_HID + c0);
        #pragma unroll
        for (int i = 0; i < 8; ++i) acc[i] = (float)v0[i] + (float)v1[i];
    }
    #pragma unroll
    for (int k = 0; k < TOPK; ++k) {
        bf16x8 v = *(const bf16x8*)(P + (size_t)ss[k] * D_HID + c0);
        float w = ww[k];
        #pragma unroll
        for (int i = 0; i < 8; ++i) acc[i] += w * (float)v[i];
    }
    float4 o0 = {acc[0], acc[1], acc[2], acc[3]};
    float4 o1 = {acc[4], acc[5], acc[6], acc[7]};
    *(float4*)(out + (size_t)t * D_HID + c0) = o0;
    *(float4*)(out + (size_t)t * D_HID + c0 + 4) = o1;
}

extern "C" void kernel_launch(void* const* d_in, const int* in_sizes, int n_in,
                              void* d_out, int out_size, void* d_ws, size_t ws_size,
                              hipStream_t stream) {
    const float* x  = (const float*)d_in[0];
    const float* wr = (const float*)d_in[1];
    const float* wg = (const float*)d_in[2];
    const float* wu = (const float*)d_in[3];
    const float* wd = (const float*)d_in[4];
    const float* sg = (const float*)d_in[5];
    const float* su = (const float*)d_in[6];
    const float* sd = (const float*)d_in[7];
    float* out = (float*)d_out;

    char* w = (char*)d_ws;
    int*   counts   = (int*)(w + 0);        // 32 ints
    int*   cursors  = (int*)(w + 256);      // 32 ints
    int*   offs     = (int*)(w + 512);      // 35 ints
    int*   tok_e    = (int*)(w + 8192);                 // 12288 ints
    float* tok_w    = (float*)(w + 8192 + 49152);       // 12288 floats
    int*   slots    = (int*)(w + 8192 + 2 * 49152);     // 12288 ints
    int*   rowtok   = (int*)(w + 8192 + 3 * 49152);     // 16384 ints
    bf16*  H        = (bf16*)(w + 262144);                                  // 16384 x 1408 bf16
    bf16*  P        = (bf16*)(w + 262144 + (size_t)ROWS_TOTAL * F_INT * 2); // 16384 x 2048 bf16
    bf16*  Xb       = (bf16*)(w + 262144 + (size_t)ROWS_TOTAL * F_INT * 2
                                        + (size_t)ROWS_TOTAL * D_HID * 2);  // 2048 x 2048 bf16

    hipMemsetAsync(counts, 0, 128, stream);
    k_xcvt<<<T_TOK * D_HID / 2048, 256, 0, stream>>>(x, Xb);
    k_router<<<T_TOK, 256, 0, stream>>>(x, wr, counts, tok_e, tok_w);
    k_plan<<<1, 64, 0, stream>>>(counts, offs, cursors);
    k_assign<<<T_TOK / 256, 256, 0, stream>>>(tok_e, offs, cursors, slots, rowtok);
    k_gateup<<<MAXT_GU * (F_INT / 128), 256, 0, stream>>>(
        Xb, wg, wu, sg, su, rowtok, counts, offs, H);
    k_down<<<MAXT_DN * (D_HID / 128), 256, 0, stream>>>(
        H, wd, sd, counts, offs, P);
    k_combine<<<T_TOK, 256, 0, stream>>>(P, slots, tok_w, out);
}